// Round 7
// baseline (233.556 us; speedup 1.0000x reference)
//
#include <hip/hip_runtime.h>

// Problem constants (from reference)
#define B_ROWS  32768
#define S_SAMP  16
#define NRELS   238
#define DIM     256
#define N_NODES 100000
#define NF4     ((N_NODES * DIM) / 4)     // 6,400,000 float4 elements of F
#define CONV_BLOCKS (NF4 / 256)           // 25,000

typedef __attribute__((ext_vector_type(8))) short  short8;    // 8 x bf16 (4 VGPRs)
typedef __attribute__((ext_vector_type(8))) unsigned short ushort8;
typedef __attribute__((ext_vector_type(4))) float  f32x4;     // MFMA accumulator

static __device__ __forceinline__ unsigned short f2bf(float f) {
    unsigned int u = __float_as_uint(f);
    u += 0x7FFFu + ((u >> 16) & 1u);   // round-to-nearest-even
    return (unsigned short)(u >> 16);
}
static __device__ __forceinline__ float bf2f(unsigned short u) {
    return __uint_as_float(((unsigned int)u) << 16);
}

// DMA one 16B chunk per lane straight into LDS (no VGPR round-trip).
// LDS dest is wave-uniform; lane i lands at ldsbase + i*16.
#define GLOAD_LDS16(gp, lp)                                                      \
    __builtin_amdgcn_global_load_lds(                                            \
        (const __attribute__((address_space(1))) void*)(gp),                     \
        (__attribute__((address_space(3))) void*)(lp), 16, 0, 0)

// Kernel 1 (prep): blocks [0,CONV_BLOCKS) stream-convert F fp32 -> Fb bf16.
// Remaining 256 blocks build Wb = bf16(W) and RWb = bf16(RW) [256][256]
// (native [n][r] layout, zero-padded r 238->256).
__global__ __launch_bounds__(256) void prep_kernel(const float* __restrict__ F,
                                                   const float* __restrict__ W,
                                                   const float* __restrict__ RW,
                                                   unsigned short* __restrict__ Fb,
                                                   unsigned short* __restrict__ Wb,
                                                   unsigned short* __restrict__ RWb) {
    if (blockIdx.x < CONV_BLOCKS) {
        int i = blockIdx.x * 256 + threadIdx.x;       // float4 index
        float4 v = ((const float4*)F)[i];
        ushort4 p;
        p.x = f2bf(v.x); p.y = f2bf(v.y); p.z = f2bf(v.z); p.w = f2bf(v.w);
        ((ushort4*)Fb)[i] = p;
    } else {
        int i = (blockIdx.x - CONV_BLOCKS) * 256 + threadIdx.x;
        if (i < DIM * DIM) {
            Wb[i] = f2bf(W[i]);
            int n = i >> 8;      // output dim
            int k = i & 255;     // relation id (padded K)
            RWb[i] = (k < NRELS) ? f2bf(RW[n * NRELS + k]) : (unsigned short)0;
        }
    }
}

// Kernel 2 (fused main): one block = 32 output rows, 4 waves, 1024 blocks,
// 44.5 KB LDS -> 3 blocks/CU, 12 waves/CU.
//
// R6 post-mortem: global_load_lds with per-row vmcnt(0) drains serialized
// rows (79.9us). This version is the COUNTED-vmcnt pipeline (T4): per wave,
// 3 rotating 2KB chunk buffers; chunk = 4 samples (2 DMA instr, each 1KB =
// 2 samples: lanes 0-31 even sample's 512B row, 32-63 odd's). Steady loop:
//   s_waitcnt vmcnt(2)   (chunk k landed; k+1 still in flight)
//   issue chunk k+2 DMAs (into buffer of chunk k-1, consumed last iter)
//   consume chunk k      (2 ds_read_b128/lane + bf16 sums)
// -> 4KB in flight per wave continuously, ~48KB/CU outstanding.
// Indices preloaded as one int2/lane (8 rows x 16 samples per wave) and
// broadcast per-DMA via __shfl, so vmcnt counts ONLY feature DMAs.
//
// Relation mean is LINEAR in a per-row relation-count histogram ->
// 4-bit packed LDS histogram, expanded to exact bf16 counts/16 into Cs
// (aliases the stage buffer, dead after phase 1), appended as K 256..511
// of the MFMA with B = RWb.
//
// Phase 2: wave `wid` owns n-tiles wid*4..wid*4+3; FOUR sequential
// Breg[4][4] batches (Wb k0-127, Wb k128-255, RWb k0-127, RWb k128-255);
// 2 m-tiles x 16 k-steps of 16x16x32 MFMA off padded LDS tiles (stride
// 264 ushorts). Epilogue: ReLU, fp32 store.
__global__ __launch_bounds__(256, 3) void fused_kernel(const int* __restrict__ nbr,
                                                       const int* __restrict__ rels,
                                                       const unsigned short* __restrict__ Fb,
                                                       const unsigned short* __restrict__ RWb,
                                                       const unsigned short* __restrict__ Wb,
                                                       float* __restrict__ out) {
    __shared__ __align__(16) char stage[4][6144];   // 3 x 2KB chunk bufs per wave
    __shared__ unsigned short As[32][264];          // feature means (bf16)
    __shared__ unsigned int   cnt4[32][32];         // 4-bit packed histogram
    // Cs aliases the stage buffers (free after phase 1): 32*264*2 = 16.9 KB
    unsigned short (*Cs)[264] = (unsigned short (*)[264])&stage[0][0];

    const int tid  = threadIdx.x;             // 0..255
    const int lane = tid & 63;
    const int wid  = __builtin_amdgcn_readfirstlane(tid >> 6);   // 0..3
    const int half = lane >> 5;       // 0: even samples, 1: odd samples
    const int li   = lane & 31;       // 16B chunk: dims [li*8, li*8+8)
    const int col0 = lane & 15;
    const int quad = lane >> 4;
    const int r0g  = blockIdx.x * 32;
    char* sbuf = &stage[wid][0];      // wave-uniform stage base

    // ---- zero histogram (1024 words / 256 threads) ----
    unsigned int* c4 = (unsigned int*)cnt4;
    c4[tid] = 0u; c4[tid + 256] = 0u; c4[tid + 512] = 0u; c4[tid + 768] = 0u;
    __syncthreads();

    // ---- histogram: 512 samples/block, 2 per thread; nibble-packed ----
    {
        const int hr = tid >> 3;            // row 0..31
        const int hs = tid & 7;             // sample 0..7 (+8)
        int rid0 = rels[(r0g + hr) * S_SAMP + hs];
        int rid1 = rels[(r0g + hr) * S_SAMP + hs + 8];
        atomicAdd(&cnt4[hr][rid0 >> 3], 1u << ((rid0 & 7) * 4));
        atomicAdd(&cnt4[hr][rid1 >> 3], 1u << ((rid1 & 7) * 4));
    }

    // ---- Phase 1: counted-vmcnt DMA gather pipeline, 8 rows/wave ----
    // Index block: lane e holds samples 2e,2e+1 of flat [8 rows][16 samples].
    // Holder of (row i, sample t) = lane i*8 + t/2, component t&1.
    const int2 my = ((const int2*)(nbr + (size_t)(r0g + wid * 8) * S_SAMP))[lane];
    const float sc = 1.0f / 16.0f;
    float af[8];

    // chunk k (0..31): row i=k>>2, quad q=k&3 -> samples 4q..4q+3.
    // buffer: sbuf + (k%3)*2048. instr s covers samples 4q+2s / 4q+2s+1.
#define ISSUE_CHUNK(k)                                                            \
    {                                                                             \
        const int i_ = (k) >> 2, q_ = (k) & 3;                                    \
        const int h_ = i_ * 8 + 2 * q_;                                           \
        int ax0 = __shfl(my.x, h_),     ay0 = __shfl(my.y, h_);                   \
        int ax1 = __shfl(my.x, h_ + 1), ay1 = __shfl(my.y, h_ + 1);               \
        int n0 = half ? ay0 : ax0;                                                \
        int n1 = half ? ay1 : ax1;                                                \
        asm volatile("s_waitcnt lgkmcnt(0)" ::: "memory");                        \
        GLOAD_LDS16(Fb + (size_t)n0 * DIM + li * 8, sbuf + ((k) % 3) * 2048);     \
        GLOAD_LDS16(Fb + (size_t)n1 * DIM + li * 8, sbuf + ((k) % 3) * 2048 + 1024);\
    }

    ISSUE_CHUNK(0);
    ISSUE_CHUNK(1);
#pragma unroll
    for (int k = 0; k < 32; ++k) {
        if (k < 31) asm volatile("s_waitcnt vmcnt(2)" ::: "memory");
        else        asm volatile("s_waitcnt vmcnt(0)" ::: "memory");
        if (k + 2 < 32) ISSUE_CHUNK(k + 2);
        // consume chunk k: lane's 2 samples (its half) from slots 0,1
        if ((k & 3) == 0) {
#pragma unroll
            for (int j = 0; j < 8; ++j) af[j] = 0.f;
        }
        {
            const char* cb = sbuf + (k % 3) * 2048 + half * 512 + li * 16;
            ushort8 f0 = *(const ushort8*)(cb);
            ushort8 f1 = *(const ushort8*)(cb + 1024);
#pragma unroll
            for (int j = 0; j < 8; ++j) af[j] += bf2f(f0[j]) + bf2f(f1[j]);
        }
        if ((k & 3) == 3) {
            // row complete: cross-half merge, pack, store
            const int row_l = wid * 8 + (k >> 2);
            ushort8 pk;
#pragma unroll
            for (int j = 0; j < 8; ++j) {
                float full = af[j] + __shfl_xor(af[j], 32, 64);
                pk[j] = f2bf(full * sc);
            }
            if (!half) *(ushort8*)&As[row_l][li * 8] = pk;
        }
    }
#undef ISSUE_CHUNK

    // ---- B preload batch A (Wb k 0..127), overlaps barrier wait ----
    short8 Breg[4][4];
#pragma unroll
    for (int j = 0; j < 4; ++j)
#pragma unroll
        for (int kk = 0; kk < 4; ++kk)
            Breg[j][kk] = *(const short8*)(Wb + (size_t)((wid * 4 + j) * 16 + col0) * DIM
                                              + kk * 32 + quad * 8);
    __syncthreads();   // all staging + As complete; stage reusable as Cs

    // ---- expand histogram -> Cs bf16 (counts/16 is bf16-exact) ----
    {
        const int rr = tid >> 3;            // row 0..31
        const int kb = (tid & 7) * 32;      // k-range base
#pragma unroll
        for (int g = 0; g < 4; ++g) {
            unsigned int w = cnt4[rr][(kb >> 3) + g];
            ushort8 ck;
#pragma unroll
            for (int j = 0; j < 8; ++j)
                ck[j] = f2bf((float)((w >> (4 * j)) & 0xFu) * 0.0625f);
            *(ushort8*)&Cs[rr][kb + g * 8] = ck;
        }
    }
    __syncthreads();

    // ---- Phase 2: 32x64 output tile per wave via MFMA, K = 512 ----
    f32x4 acc[2][4];
#pragma unroll
    for (int mt = 0; mt < 2; ++mt)
#pragma unroll
        for (int j = 0; j < 4; ++j) acc[mt][j] = (f32x4){0.f, 0.f, 0.f, 0.f};

    // batch A: As x Wb, k 0..127
#pragma unroll
    for (int mt = 0; mt < 2; ++mt) {
        const int mrow = mt * 16 + col0;
#pragma unroll
        for (int kk = 0; kk < 4; ++kk) {
            short8 a = *(const short8*)&As[mrow][kk * 32 + quad * 8];
#pragma unroll
            for (int j = 0; j < 4; ++j)
                acc[mt][j] = __builtin_amdgcn_mfma_f32_16x16x32_bf16(a, Breg[j][kk], acc[mt][j], 0, 0, 0);
        }
    }
    // batch B: As x Wb, k 128..255
#pragma unroll
    for (int j = 0; j < 4; ++j)
#pragma unroll
        for (int kk = 0; kk < 4; ++kk)
            Breg[j][kk] = *(const short8*)(Wb + (size_t)((wid * 4 + j) * 16 + col0) * DIM
                                              + (kk + 4) * 32 + quad * 8);
#pragma unroll
    for (int mt = 0; mt < 2; ++mt) {
        const int mrow = mt * 16 + col0;
#pragma unroll
        for (int kk = 0; kk < 4; ++kk) {
            short8 a = *(const short8*)&As[mrow][(kk + 4) * 32 + quad * 8];
#pragma unroll
            for (int j = 0; j < 4; ++j)
                acc[mt][j] = __builtin_amdgcn_mfma_f32_16x16x32_bf16(a, Breg[j][kk], acc[mt][j], 0, 0, 0);
        }
    }
    // batch C: Cs x RWb, k 0..127  (relation histogram GEMM)
#pragma unroll
    for (int j = 0; j < 4; ++j)
#pragma unroll
        for (int kk = 0; kk < 4; ++kk)
            Breg[j][kk] = *(const short8*)(RWb + (size_t)((wid * 4 + j) * 16 + col0) * DIM
                                               + kk * 32 + quad * 8);
#pragma unroll
    for (int mt = 0; mt < 2; ++mt) {
        const int mrow = mt * 16 + col0;
#pragma unroll
        for (int kk = 0; kk < 4; ++kk) {
            short8 a = *(const short8*)&Cs[mrow][kk * 32 + quad * 8];
#pragma unroll
            for (int j = 0; j < 4; ++j)
                acc[mt][j] = __builtin_amdgcn_mfma_f32_16x16x32_bf16(a, Breg[j][kk], acc[mt][j], 0, 0, 0);
        }
    }
    // batch D: Cs x RWb, k 128..255
#pragma unroll
    for (int j = 0; j < 4; ++j)
#pragma unroll
        for (int kk = 0; kk < 4; ++kk)
            Breg[j][kk] = *(const short8*)(RWb + (size_t)((wid * 4 + j) * 16 + col0) * DIM
                                               + (kk + 4) * 32 + quad * 8);
#pragma unroll
    for (int mt = 0; mt < 2; ++mt) {
        const int mrow = mt * 16 + col0;
#pragma unroll
        for (int kk = 0; kk < 4; ++kk) {
            short8 a = *(const short8*)&Cs[mrow][(kk + 4) * 32 + quad * 8];
#pragma unroll
            for (int j = 0; j < 4; ++j)
                acc[mt][j] = __builtin_amdgcn_mfma_f32_16x16x32_bf16(a, Breg[j][kk], acc[mt][j], 0, 0, 0);
        }
    }

    // ---- Epilogue: ReLU, store (relation term already accumulated) ----
#pragma unroll
    for (int mt = 0; mt < 2; ++mt) {
#pragma unroll
        for (int j = 0; j < 4; ++j) {
            const int col = (wid * 4 + j) * 16 + col0;
#pragma unroll
            for (int i2 = 0; i2 < 4; ++i2) {
                const int r_l = mt * 16 + quad * 4 + i2;
                float v = acc[mt][j][i2];
                out[(size_t)(r0g + r_l) * DIM + col] = v > 0.f ? v : 0.f;
            }
        }
    }
}

extern "C" void kernel_launch(void* const* d_in, const int* in_sizes, int n_in,
                              void* d_out, int out_size, void* d_ws, size_t ws_size,
                              hipStream_t stream) {
    const int*   neighbors = (const int*)d_in[0];
    const int*   relations = (const int*)d_in[1];
    const float* features  = (const float*)d_in[2];
    const float* weight    = (const float*)d_in[3];
    const float* relw      = (const float*)d_in[4];
    float* out = (float*)d_out;

    char* ws = (char*)d_ws;
    // ws layout (bytes): Wb  bf16 [256*256]    at 0       (131072)
    //                    RWb bf16 [256*256]    at 131072  (131072)
    //                    Fb  bf16 [100000*256] at 262144  (51200000)  ~51.5 MB
    unsigned short* Wb  = (unsigned short*)ws;
    unsigned short* RWb = (unsigned short*)(ws + 131072);
    unsigned short* Fb  = (unsigned short*)(ws + 262144);

    prep_kernel<<<CONV_BLOCKS + 256, 256, 0, stream>>>(features, weight, relw, Fb, Wb, RWb);
    fused_kernel<<<B_ROWS / 32, 256, 0, stream>>>(neighbors, relations, Fb, RWb, Wb, out);
}